// Round 1
// baseline (237.492 us; speedup 1.0000x reference)
//
#include <hip/hip_runtime.h>

// NonSpikingInput: RK2 leaky integrator, closed form per step:
//   k1 = i - 5v ; k2 = 0.75*k1 ; v' = v + 0.1*k2  ==>  v' = 0.625*v + 0.075*i
// v[n,-1] = 0. Output = full history, (4096, 8192) fp32.
//
// Memory-bound: 268 MB @ ~6.3 TB/s -> ~43 us floor.
//
// Strategy: one 256-thread block per neuron row.
//  - Stage the row (32 KiB) into LDS with per-chunk padding: 32 floats + 4 pad
//    -> chunk stride 144 B == 16 mod 128 B, so lane-strided ds_read_b128 has
//    the same bank pattern as contiguous 16 B reads (conflict-free, 16B-aligned).
//  - Each thread scans CHUNK=32 elems after a 64-step warm-up from v=0
//    (A^64 ~ 8e-14: initial-condition error negligible; threads 0,1 exact
//    via b=0 predication).
//  - Results stored direct to global as float4 (L2 merges the 128B-strided
//    16B stores into full dirty lines).

constexpr int TT    = 8192;  // time steps per row
constexpr int BLK   = 256;   // threads per block
constexpr int CHUNK = 32;    // TT / BLK
constexpr int CPAD  = 36;    // padded chunk stride in floats (144 B)

__global__ __launch_bounds__(BLK, 4)
void neuron_scan(const float* __restrict__ in, float* __restrict__ out) {
    __shared__ float s[BLK * CPAD];  // 9216 floats = 36 KiB -> 4 blocks/CU
    const float A = 0.625f;
    const float B = 0.075f;

    const int t = threadIdx.x;
    const size_t row = (size_t)blockIdx.x * TT;

    // Phase 1: coalesced global -> LDS (padded layout).
    const float4* src = (const float4*)(in + row);
    #pragma unroll
    for (int k = 0; k < 8; ++k) {
        const int o4 = t + BLK * k;        // float4 index within row
        const float4 val = src[o4];
        const int o = o4 << 2;             // logical float offset
        *(float4*)(s + (o >> 5) * CPAD + (o & 31)) = val;
    }
    __syncthreads();

    // Phase 2: 64-step warm-up over the two preceding chunks.
    float v = 0.0f;
    #pragma unroll
    for (int w = 2; w >= 1; --w) {
        const int c = t - w;
        const float4* p = (const float4*)(s + (c < 0 ? 0 : c * CPAD));
        const float b = (c >= 0) ? B : 0.0f;   // b=0 keeps v exactly 0 for edge threads
        #pragma unroll
        for (int q = 0; q < 8; ++q) {
            const float4 x = p[q];
            v = fmaf(A, v, b * x.x);
            v = fmaf(A, v, b * x.y);
            v = fmaf(A, v, b * x.z);
            v = fmaf(A, v, b * x.w);
        }
    }

    // Phase 3: scan own chunk, store as float4.
    const float4* pc = (const float4*)(s + t * CPAD);
    float4* dst = (float4*)(out + row + (size_t)t * CHUNK);
    #pragma unroll
    for (int q = 0; q < 8; ++q) {
        const float4 x = pc[q];
        float4 o;
        v = fmaf(A, v, B * x.x); o.x = v;
        v = fmaf(A, v, B * x.y); o.y = v;
        v = fmaf(A, v, B * x.z); o.z = v;
        v = fmaf(A, v, B * x.w); o.w = v;
        dst[q] = o;
    }
}

extern "C" void kernel_launch(void* const* d_in, const int* in_sizes, int n_in,
                              void* d_out, int out_size, void* d_ws, size_t ws_size,
                              hipStream_t stream) {
    const float* in = (const float*)d_in[0];
    float* out = (float*)d_out;
    const int n_rows = in_sizes[0] / TT;   // 4096
    neuron_scan<<<dim3(n_rows), dim3(BLK), 0, stream>>>(in, out);
}

// Round 3
// 232.744 us; speedup vs baseline: 1.0204x; 1.0204x over previous
//
#include <hip/hip_runtime.h>

// NonSpikingInput: RK2 leaky integrator, closed form per step:
//   v' = 0.625*v + 0.075*i   (E_REST = I_BIAS = 0)
// Output = full history, (4096, 8192) fp32. Memory-bound: 268 MB -> ~43 us floor.
//
// R1 -> R3 change: stores were 16 B/lane at 128 B stride (64 lines per wave
// store, partial-dirty merges) -> round-trip results through LDS and store
// contiguous 1 KiB/wave, same addressing as the coalesced load phase.
// (R2 failed to compile: __builtin_nontemporal_store needs a native vector
// type, not HIP_vector_type<float,4> -> use ext_vector_type(4).)
//
// Structure (one 256-thread block per row):
//  1. coalesced global->LDS, padded chunks (32 floats + 4 pad = 144 B stride;
//     144 % 128 == 16 -> lane-strided b128 access conflict-free)
//  2. 64-step warm-up from v=0 over chunks t-2, t-1 (A^64 ~ 8e-14)
//  3. in-place scan of own chunk in LDS
//  4. coalesced LDS->global store (nontemporal)

typedef float fx4 __attribute__((ext_vector_type(4)));

constexpr int TT    = 8192;  // time steps per row
constexpr int BLK   = 256;   // threads per block
constexpr int CHUNK = 32;    // TT / BLK
constexpr int CPAD  = 36;    // padded chunk stride in floats (144 B)

__global__ __launch_bounds__(BLK, 4)
void neuron_scan(const float* __restrict__ in, float* __restrict__ out) {
    __shared__ float s[BLK * CPAD];  // 36 KiB -> 4 blocks/CU
    const float A = 0.625f;
    const float B = 0.075f;

    const int t = threadIdx.x;
    const size_t row = (size_t)blockIdx.x * TT;

    // Phase 1: coalesced global -> LDS (padded layout).
    const fx4* src = (const fx4*)(in + row);
    #pragma unroll
    for (int k = 0; k < 8; ++k) {
        const int o4 = t + BLK * k;        // float4 index within row
        const fx4 val = src[o4];
        const int o = o4 << 2;             // logical float offset
        *(fx4*)(s + (o >> 5) * CPAD + (o & 31)) = val;
    }
    __syncthreads();

    // Phase 2: 64-step warm-up over the two preceding chunks.
    float v = 0.0f;
    #pragma unroll
    for (int w = 2; w >= 1; --w) {
        const int c = t - w;
        const fx4* p = (const fx4*)(s + (c < 0 ? 0 : c * CPAD));
        const float b = (c >= 0) ? B : 0.0f;   // b=0 keeps v exactly 0 for edge threads
        #pragma unroll
        for (int q = 0; q < 8; ++q) {
            const fx4 x = p[q];
            v = fmaf(A, v, b * x.x);
            v = fmaf(A, v, b * x.y);
            v = fmaf(A, v, b * x.z);
            v = fmaf(A, v, b * x.w);
        }
    }
    __syncthreads();   // neighbors' warm-up reads of chunk t must finish
                       // before thread t overwrites it

    // Phase 3: in-place scan of own chunk.
    fx4* pc = (fx4*)(s + t * CPAD);
    #pragma unroll
    for (int q = 0; q < 8; ++q) {
        fx4 x = pc[q];
        v = fmaf(A, v, B * x.x); x.x = v;
        v = fmaf(A, v, B * x.y); x.y = v;
        v = fmaf(A, v, B * x.z); x.z = v;
        v = fmaf(A, v, B * x.w); x.w = v;
        pc[q] = x;
    }
    __syncthreads();

    // Phase 4: coalesced LDS -> global store (mirror of phase 1).
    fx4* dst = (fx4*)(out + row);
    #pragma unroll
    for (int k = 0; k < 8; ++k) {
        const int o4 = t + BLK * k;
        const int o = o4 << 2;
        const fx4 val = *(const fx4*)(s + (o >> 5) * CPAD + (o & 31));
        __builtin_nontemporal_store(val, dst + o4);
    }
}

extern "C" void kernel_launch(void* const* d_in, const int* in_sizes, int n_in,
                              void* d_out, int out_size, void* d_ws, size_t ws_size,
                              hipStream_t stream) {
    const float* in = (const float*)d_in[0];
    float* out = (float*)d_out;
    const int n_rows = in_sizes[0] / TT;   // 4096
    neuron_scan<<<dim3(n_rows), dim3(BLK), 0, stream>>>(in, out);
}